// Round 13
// baseline (41.086 us; speedup 1.0000x reference)
//
#include <hip/hip_runtime.h>

#define BS 16
#define NP 500000
#define NQ (NP / 4)     // 125000 quads per scene
#define NOBJ 16
#define NSEG3 48        // NOBJ*3
#define GX 512          // blocks per scene (8192 total: 2x oversubscribed, fine tail)
#define BT 128          // threads per block (2 waves)
#define NSUB 16         // LDS sub-tables, selected by tid&15

typedef float f32x4 __attribute__((ext_vector_type(4)));  // native vec for nontemporal store

// ws word layout (all slots written unconditionally every call -> no init pass):
//   slotmin : [0, 393216)            BS*GX*48   per-block min keys
//   slotmax : [393216, 786432)                  per-block max keys
//   slotmask: [786432, 794624)       BS*GX      per-block presence bitmask
// total 3.1 MB << ws_size (~375 MB per the poison fill's WRITE_SIZE)
#define WS_SMAX 393216
#define WS_SMSK 786432

// Order-preserving float -> uint key (min/max over keys == min/max over floats)
__device__ __forceinline__ unsigned fkey(float f) {
    unsigned u = __float_as_uint(f);
    return (u & 0x80000000u) ? ~u : (u | 0x80000000u);
}
__device__ __forceinline__ float keyf(unsigned k) {
    unsigned u = (k & 0x80000000u) ? (k ^ 0x80000000u) : ~k;
    return __uint_as_float(u);
}

// Main pass: R8's proven inner loop, re-grained: 128-thread blocks, 8192 blocks.
// 16 resident blocks/CU (32 waves = full occupancy) + 16 queued -> launch ramp,
// XCD imbalance and per-block tail quantum all smoothed (the one parameter
// never varied across 5 null instruction-level restructurings).
__global__ __launch_bounds__(BT, 8) void kmain(const float* __restrict__ pc,
                                               const int* __restrict__ tag,
                                               unsigned* __restrict__ ws,
                                               float* __restrict__ out) {
    __shared__ unsigned lmin[NSUB * NSEG3], lmax[NSUB * NSEG3];
    __shared__ unsigned lmask;
    const int b = blockIdx.y, x = blockIdx.x, tid = threadIdx.x;
    if (tid == 0) lmask = 0u;
    for (int j = tid; j < NSUB * NSEG3; j += BT) { lmin[j] = 0xFFFFFFFFu; lmax[j] = 0u; }
    __syncthreads();

    const int sub = tid & (NSUB - 1);
    const float fb = (float)(b * NOBJ);
    const int4*   tag4 = (const int4*)(tag + (size_t)b * NP);
    const float4* pc4  = (const float4*)(pc + (size_t)b * NP * 3);
    f32x4* out4 = (f32x4*)(out + 2304 + (size_t)b * NP);  // 2304 floats = keypoints
    unsigned m = 0u;
    for (int i = x * BT + tid; i < NQ; i += GX * BT) {
        int4 t = tag4[i];
        float4 f0 = pc4[i * 3 + 0];  // x0 y0 z0 x1
        float4 f1 = pc4[i * 3 + 1];  // y1 z1 x2 y2
        float4 f2 = pc4[i * 3 + 2];  // z2 x3 y3 z3
        f32x4 ob = {fb + (float)t.x, fb + (float)t.y, fb + (float)t.z, fb + (float)t.w};
        __builtin_nontemporal_store(ob, &out4[i]);
        m |= (1u << t.x) | (1u << t.y) | (1u << t.z) | (1u << t.w);
        // idx = t*48 + c*16 + sub -> bank sub + 16*((t+c)&1), ~2 lanes/bank
        int a0 = t.x * 48 + sub, a1 = t.y * 48 + sub, a2 = t.z * 48 + sub, a3 = t.w * 48 + sub;
        unsigned k;
        k = fkey(f0.x); atomicMin(&lmin[a0 +  0], k); atomicMax(&lmax[a0 +  0], k);
        k = fkey(f0.y); atomicMin(&lmin[a0 + 16], k); atomicMax(&lmax[a0 + 16], k);
        k = fkey(f0.z); atomicMin(&lmin[a0 + 32], k); atomicMax(&lmax[a0 + 32], k);
        k = fkey(f0.w); atomicMin(&lmin[a1 +  0], k); atomicMax(&lmax[a1 +  0], k);
        k = fkey(f1.x); atomicMin(&lmin[a1 + 16], k); atomicMax(&lmax[a1 + 16], k);
        k = fkey(f1.y); atomicMin(&lmin[a1 + 32], k); atomicMax(&lmax[a1 + 32], k);
        k = fkey(f1.z); atomicMin(&lmin[a2 +  0], k); atomicMax(&lmax[a2 +  0], k);
        k = fkey(f1.w); atomicMin(&lmin[a2 + 16], k); atomicMax(&lmax[a2 + 16], k);
        k = fkey(f2.x); atomicMin(&lmin[a2 + 32], k); atomicMax(&lmax[a2 + 32], k);
        k = fkey(f2.y); atomicMin(&lmin[a3 +  0], k); atomicMax(&lmax[a3 +  0], k);
        k = fkey(f2.z); atomicMin(&lmin[a3 + 16], k); atomicMax(&lmax[a3 + 16], k);
        k = fkey(f2.w); atomicMin(&lmin[a3 + 32], k); atomicMax(&lmax[a3 + 32], k);
    }
    atomicOr(&lmask, m);
    __syncthreads();

    const int slot = b * GX + x;
    if (tid < NSEG3) {
        unsigned mn = 0xFFFFFFFFu, mx = 0u;
        #pragma unroll
        for (int s = 0; s < NSUB; ++s) {
            mn = min(mn, lmin[tid * NSUB + s]);
            mx = max(mx, lmax[tid * NSUB + s]);
        }
        ws[slot * NSEG3 + tid] = mn;
        ws[WS_SMAX + slot * NSEG3 + tid] = mx;
    }
    if (tid == 0) ws[WS_SMSK + slot] = lmask;
}

// K3: per-scene reduction of GX=512 block partials + keypoints epilogue.
// 512 threads / 8 waves: wave w reduces slots [w*64, w*64+64) for min AND max
// (lanes 0-47); lanes 48-55 OR the wave's 64 slot masks (8 each).
__global__ __launch_bounds__(512) void k3(const unsigned* __restrict__ ws,
                                          float* __restrict__ out) {
    __shared__ unsigned pmin[8][NSEG3], pmax[8][NSEG3];
    __shared__ unsigned smin[NSEG3], smax[NSEG3];
    __shared__ unsigned smask;
    __shared__ float lut[NOBJ];
    const int b = blockIdx.x, tid = threadIdx.x;
    const int wave = tid >> 6, lane = tid & 63;

    if (tid == 0) smask = 0u;
    __syncthreads();

    if (lane < NSEG3) {
        unsigned mn = 0xFFFFFFFFu, mx = 0u;
        const int x0 = wave * (GX / 8);
        #pragma unroll 8
        for (int x2 = x0; x2 < x0 + GX / 8; ++x2) {
            mn = min(mn, ws[(b * GX + x2) * NSEG3 + lane]);
            mx = max(mx, ws[WS_SMAX + (b * GX + x2) * NSEG3 + lane]);
        }
        pmin[wave][lane] = mn;
        pmax[wave][lane] = mx;
    } else if (lane >= 48 && lane < 56) {
        const int base = b * GX + wave * (GX / 8) + (lane - 48) * 8;
        unsigned mm = 0u;
        #pragma unroll
        for (int j = 0; j < 8; ++j) mm |= ws[WS_SMSK + base + j];
        atomicOr(&smask, mm);
    }
    __syncthreads();

    if (tid < NSEG3) {
        unsigned mn = 0xFFFFFFFFu;
        #pragma unroll
        for (int w = 0; w < 8; ++w) mn = min(mn, pmin[w][tid]);
        smin[tid] = mn;
    } else if (tid >= 64 && tid < 64 + NSEG3) {
        const int e = tid - 64;
        unsigned mx = 0u;
        #pragma unroll
        for (int w = 0; w < 8; ++w) mx = max(mx, pmax[w][e]);
        smax[e] = mx;
    }
    __syncthreads();
    const unsigned mask = smask;

    if (tid == 0) {
        int tag_of[NOBJ];
        int r = -1;
        for (int t = 0; t < NOBJ; ++t)
            if ((mask >> t) & 1u) { ++r; tag_of[r] = t; }
        int nd = r + 1;
        // bbox rows: [min0, max0, ...] over dense ids; empty dense ids -> 0
        float bbox[32][3];
        for (int i = 0; i < NOBJ; ++i) {
            for (int c = 0; c < 3; ++c) {
                float mn = 0.f, mx = 0.f;
                if (i < nd) {
                    int t = tag_of[i];
                    mn = keyf(smin[t * 3 + c]);
                    mx = keyf(smax[t * 3 + c]);
                }
                bbox[2 * i][c] = mn;
                bbox[2 * i + 1][c] = mx;
            }
        }
        float* ob = out + (size_t)b * 48 * 3;
        for (int j = 0; j < 32; ++j)
            for (int c = 0; c < 3; ++c)
                ob[j * 3 + c] = bbox[j][c];
        // faithful torch barycenter: row-major split of interleaved bbox rows
        for (int j = 0; j < 16; ++j)
            for (int c = 0; c < 3; ++c)
                ob[(32 + j) * 3 + c] = 0.5f * (bbox[j][c] + bbox[16 + j][c]);
    }

    if (mask != 0xFFFFu) {  // rare, input-determined -> deterministic; block-uniform
        if (tid < NOBJ)
            lut[tid] = (float)(__popc(mask & ((2u << tid) - 1u)) - 1 + b * NOBJ);
        __syncthreads();
        const float fb = (float)(b * NOBJ);
        float4* out4 = (float4*)(out + 2304 + (size_t)b * NP);
        for (int i = tid; i < NQ; i += 512) {
            float4 v = out4[i];
            out4[i] = make_float4(lut[(int)(v.x - fb)], lut[(int)(v.y - fb)],
                                  lut[(int)(v.z - fb)], lut[(int)(v.w - fb)]);
        }
    }
}

extern "C" void kernel_launch(void* const* d_in, const int* in_sizes, int n_in,
                              void* d_out, int out_size, void* d_ws, size_t ws_size,
                              hipStream_t stream) {
    const float* pc  = (const float*)d_in[0];
    const int*   tag = (const int*)d_in[1];
    float* out = (float*)d_out;
    unsigned* ws = (unsigned*)d_ws;

    kmain<<<dim3(GX, BS), BT, 0, stream>>>(pc, tag, ws, out);
    k3<<<BS, 512, 0, stream>>>(ws, out);
}

// Round 14
// 39.051 us; speedup vs baseline: 1.0521x; 1.0521x over previous
//
#include <hip/hip_runtime.h>

#define BS 16
#define NP 500000
#define NQ (NP / 4)     // 125000 quads per scene
#define NOBJ 16
#define NSEG3 48        // NOBJ*3
#define GX 128          // blocks per scene (512 waves/scene >= 489 windows)
#define NSUB 16         // LDS sub-tables, selected by lane&15
#define WQ 256          // quads per wave-window (4 per lane)

typedef float f32x4 __attribute__((ext_vector_type(4)));  // native vec for nontemporal store

// ws word layout (all slots written unconditionally every call -> no init pass):
//   slotmin : [0, 98304)         BS*GX*48   per-block min keys
//   slotmax : [98304, 196608)               per-block max keys
//   slotmask: [196608, 198656)   BS*GX      per-block presence bitmask
#define WS_SMAX 98304
#define WS_SMSK 196608

// Order-preserving float -> uint key (min/max over keys == min/max over floats)
__device__ __forceinline__ unsigned fkey(float f) {
    unsigned u = __float_as_uint(f);
    return (u & 0x80000000u) ? ~u : (u | 0x80000000u);
}
__device__ __forceinline__ float keyf(unsigned k) {
    unsigned u = (k & 0x80000000u) ? (k ^ 0x80000000u) : ~k;
    return __uint_as_float(u);
}

// 24 LDS atomics for one quad (tags T, coords F0/F1/F2); idx = t*48 + c*16 + sub
#define ATOMS(T, F0, F1, F2) do {                                                   \
    int a0_ = (T).x * 48 + sub, a1_ = (T).y * 48 + sub;                             \
    int a2_ = (T).z * 48 + sub, a3_ = (T).w * 48 + sub;                             \
    unsigned k_;                                                                     \
    k_ = fkey((F0).x); atomicMin(&lmin[a0_ +  0], k_); atomicMax(&lmax[a0_ +  0], k_); \
    k_ = fkey((F0).y); atomicMin(&lmin[a0_ + 16], k_); atomicMax(&lmax[a0_ + 16], k_); \
    k_ = fkey((F0).z); atomicMin(&lmin[a0_ + 32], k_); atomicMax(&lmax[a0_ + 32], k_); \
    k_ = fkey((F0).w); atomicMin(&lmin[a1_ +  0], k_); atomicMax(&lmax[a1_ +  0], k_); \
    k_ = fkey((F1).x); atomicMin(&lmin[a1_ + 16], k_); atomicMax(&lmax[a1_ + 16], k_); \
    k_ = fkey((F1).y); atomicMin(&lmin[a1_ + 32], k_); atomicMax(&lmax[a1_ + 32], k_); \
    k_ = fkey((F1).z); atomicMin(&lmin[a2_ +  0], k_); atomicMax(&lmax[a2_ +  0], k_); \
    k_ = fkey((F1).w); atomicMin(&lmin[a2_ + 16], k_); atomicMax(&lmax[a2_ + 16], k_); \
    k_ = fkey((F2).x); atomicMin(&lmin[a2_ + 32], k_); atomicMax(&lmax[a2_ + 32], k_); \
    k_ = fkey((F2).y); atomicMin(&lmin[a3_ +  0], k_); atomicMax(&lmax[a3_ +  0], k_); \
    k_ = fkey((F2).z); atomicMin(&lmin[a3_ + 16], k_); atomicMax(&lmax[a3_ + 16], k_); \
    k_ = fkey((F2).w); atomicMin(&lmin[a3_ + 32], k_); atomicMax(&lmax[a3_ + 32], k_); \
} while (0)

// speculative obj_batch write + presence mask for one quad
#define EMIT(T, Q) do {                                                              \
    f32x4 ob_ = {fb + (float)(T).x, fb + (float)(T).y, fb + (float)(T).z, fb + (float)(T).w}; \
    __builtin_nontemporal_store(ob_, &out4[Q]);                                      \
    m |= (1u << (T).x) | (1u << (T).y) | (1u << (T).z) | (1u << (T).w);              \
} while (0)

// Main pass (best measured config, R11 = 39.08 us): each wave owns a 256-quad
// window; lane handles quads wb+lane+64k (k=0..3); all 16 global loads issued
// before any consume. (Seven structural variants measured 39.1-41.1 us — the
// kernel runs at the memory system's mixed-stream rate; see ledger.)
__global__ __launch_bounds__(256, 4) void kmain(const float* __restrict__ pc,
                                                const int* __restrict__ tag,
                                                unsigned* __restrict__ ws,
                                                float* __restrict__ out) {
    __shared__ unsigned lmin[NSUB * NSEG3], lmax[NSUB * NSEG3];
    __shared__ unsigned lmask;
    const int b = blockIdx.y, x = blockIdx.x, tid = threadIdx.x;
    if (tid == 0) lmask = 0u;
    for (int j = tid; j < NSUB * NSEG3; j += 256) { lmin[j] = 0xFFFFFFFFu; lmax[j] = 0u; }
    __syncthreads();

    const int sub  = tid & (NSUB - 1);
    const int lane = tid & 63;
    const int wv   = x * 4 + (tid >> 6);      // wave id within scene [0,512)
    const float fb = (float)(b * NOBJ);
    const int4*   tag4 = (const int4*)(tag + (size_t)b * NP);
    const float4* pc4  = (const float4*)(pc + (size_t)b * NP * 3);
    f32x4* out4 = (f32x4*)(out + 2304 + (size_t)b * NP);  // 2304 floats = keypoints
    unsigned m = 0u;

    const int q0 = wv * WQ + lane;
    if (q0 < NQ) {                             // windows 0..488; rest idle
        const bool v1 = (q0 + 64 < NQ), v2 = (q0 + 128 < NQ), v3 = (q0 + 192 < NQ);
        const int  q1 = v1 ? q0 + 64 : q0;     // clamp: loads stay in-bounds,
        const int  q2 = v2 ? q0 + 128 : q0;    // consumes are predicated
        const int  q3 = v3 ? q0 + 192 : q0;

        // ---- issue phase: all 16 loads, no consumer in between ----
        int4 t0 = tag4[q0], t1 = tag4[q1], t2 = tag4[q2], t3 = tag4[q3];
        float4 a0 = pc4[3 * q0 + 0], a1 = pc4[3 * q0 + 1], a2 = pc4[3 * q0 + 2];
        float4 b0 = pc4[3 * q1 + 0], b1 = pc4[3 * q1 + 1], b2 = pc4[3 * q1 + 2];
        float4 c0 = pc4[3 * q2 + 0], c1 = pc4[3 * q2 + 1], c2 = pc4[3 * q2 + 2];
        float4 d0 = pc4[3 * q3 + 0], d1 = pc4[3 * q3 + 1], d2 = pc4[3 * q3 + 2];

        // ---- consume phase: quad k's DS work overlaps quads k+1.. loads ----
        EMIT(t0, q0); ATOMS(t0, a0, a1, a2);
        if (v1) { EMIT(t1, q1); ATOMS(t1, b0, b1, b2); }
        if (v2) { EMIT(t2, q2); ATOMS(t2, c0, c1, c2); }
        if (v3) { EMIT(t3, q3); ATOMS(t3, d0, d1, d2); }
    }
    atomicOr(&lmask, m);
    __syncthreads();

    const int slot = b * GX + x;
    if (tid < NSEG3) {
        unsigned mn = 0xFFFFFFFFu, mx = 0u;
        #pragma unroll
        for (int s = 0; s < NSUB; ++s) {
            mn = min(mn, lmin[tid * NSUB + s]);
            mx = max(mx, lmax[tid * NSUB + s]);
        }
        ws[slot * NSEG3 + tid] = mn;
        ws[WS_SMAX + slot * NSEG3 + tid] = mx;
    }
    if (tid == 0) ws[WS_SMSK + slot] = lmask;
}

// K3: per-scene reduction of block partials + keypoints epilogue.
__global__ __launch_bounds__(256) void k3(const unsigned* __restrict__ ws,
                                          float* __restrict__ out) {
    __shared__ unsigned pmin[4][NSEG3], pmax[4][NSEG3];
    __shared__ unsigned smin[NSEG3], smax[NSEG3];
    __shared__ unsigned smask;
    __shared__ float lut[NOBJ];
    const int b = blockIdx.x, tid = threadIdx.x;
    const int wave = tid >> 6, lane = tid & 63;

    if (tid == 0) smask = 0u;
    __syncthreads();

    if (lane < NSEG3) {
        unsigned mn = 0xFFFFFFFFu, mx = 0u;
        const int x0 = wave * (GX / 4);
        #pragma unroll 8
        for (int x2 = x0; x2 < x0 + GX / 4; ++x2) {
            mn = min(mn, ws[(b * GX + x2) * NSEG3 + lane]);
            mx = max(mx, ws[WS_SMAX + (b * GX + x2) * NSEG3 + lane]);
        }
        pmin[wave][lane] = mn;
        pmax[wave][lane] = mx;
    } else if (lane >= 56) {
        const int base = b * GX + wave * (GX / 4) + (lane - 56) * 4;
        unsigned mm = ws[WS_SMSK + base] | ws[WS_SMSK + base + 1]
                    | ws[WS_SMSK + base + 2] | ws[WS_SMSK + base + 3];
        atomicOr(&smask, mm);
    }
    __syncthreads();

    if (tid < NSEG3)
        smin[tid] = min(min(pmin[0][tid], pmin[1][tid]), min(pmin[2][tid], pmin[3][tid]));
    else if (tid >= 64 && tid < 64 + NSEG3) {
        const int e = tid - 64;
        smax[e] = max(max(pmax[0][e], pmax[1][e]), max(pmax[2][e], pmax[3][e]));
    }
    __syncthreads();
    const unsigned mask = smask;

    if (tid == 0) {
        int tag_of[NOBJ];
        int r = -1;
        for (int t = 0; t < NOBJ; ++t)
            if ((mask >> t) & 1u) { ++r; tag_of[r] = t; }
        int nd = r + 1;
        float bbox[32][3];
        for (int i = 0; i < NOBJ; ++i) {
            for (int c = 0; c < 3; ++c) {
                float mn = 0.f, mx = 0.f;
                if (i < nd) {
                    int t = tag_of[i];
                    mn = keyf(smin[t * 3 + c]);
                    mx = keyf(smax[t * 3 + c]);
                }
                bbox[2 * i][c] = mn;
                bbox[2 * i + 1][c] = mx;
            }
        }
        float* ob = out + (size_t)b * 48 * 3;
        for (int j = 0; j < 32; ++j)
            for (int c = 0; c < 3; ++c)
                ob[j * 3 + c] = bbox[j][c];
        // faithful torch barycenter: row-major split of interleaved bbox rows
        for (int j = 0; j < 16; ++j)
            for (int c = 0; c < 3; ++c)
                ob[(32 + j) * 3 + c] = 0.5f * (bbox[j][c] + bbox[16 + j][c]);
    }

    if (mask != 0xFFFFu) {  // rare, input-determined -> deterministic; block-uniform
        if (tid < NOBJ)
            lut[tid] = (float)(__popc(mask & ((2u << tid) - 1u)) - 1 + b * NOBJ);
        __syncthreads();
        const float fb = (float)(b * NOBJ);
        float4* out4 = (float4*)(out + 2304 + (size_t)b * NP);
        for (int i = tid; i < NQ; i += 256) {
            float4 v = out4[i];
            out4[i] = make_float4(lut[(int)(v.x - fb)], lut[(int)(v.y - fb)],
                                  lut[(int)(v.z - fb)], lut[(int)(v.w - fb)]);
        }
    }
}

extern "C" void kernel_launch(void* const* d_in, const int* in_sizes, int n_in,
                              void* d_out, int out_size, void* d_ws, size_t ws_size,
                              hipStream_t stream) {
    const float* pc  = (const float*)d_in[0];
    const int*   tag = (const int*)d_in[1];
    float* out = (float*)d_out;
    unsigned* ws = (unsigned*)d_ws;

    kmain<<<dim3(GX, BS), 256, 0, stream>>>(pc, tag, ws, out);
    k3<<<BS, 256, 0, stream>>>(ws, out);
}